// Round 1
// baseline (1737.681 us; speedup 1.0000x reference)
//
#include <hip/hip_runtime.h>

#define N_NODES 100000
#define N_EDGES 1600000
#define D 128
#define DH 256
#define N_GRAPHS 512
#define EPS 1e-5f

// ---------------- preprocessing ----------------

__global__ void k_count(const int* __restrict__ dst, int* __restrict__ cnt) {
    int e = blockIdx.x * 256 + threadIdx.x;
    if (e < N_EDGES) atomicAdd(&cnt[dst[e]], 1);
}

__global__ void k_dinv(const int* __restrict__ cnt, float* __restrict__ dinv) {
    int i = blockIdx.x * 256 + threadIdx.x;
    if (i < N_NODES) dinv[i] = rsqrtf((float)(cnt[i] + 1));
}

__global__ void k_scan1(const int* __restrict__ in, int* __restrict__ out,
                        int* __restrict__ bsums, int n) {
    __shared__ int tmp[256];
    int gid = blockIdx.x * 256 + threadIdx.x;
    int v = (gid < n) ? in[gid] : 0;
    tmp[threadIdx.x] = v;
    __syncthreads();
    for (int off = 1; off < 256; off <<= 1) {
        int t = (threadIdx.x >= off) ? tmp[threadIdx.x - off] : 0;
        __syncthreads();
        tmp[threadIdx.x] += t;
        __syncthreads();
    }
    if (gid < n) out[gid] = tmp[threadIdx.x] - v;  // exclusive
    if (threadIdx.x == 255) bsums[blockIdx.x] = tmp[255];
}

__global__ void k_scan2(int* __restrict__ bsums, int nb) {
    __shared__ int tmp[512];
    int v = (threadIdx.x < nb) ? bsums[threadIdx.x] : 0;
    tmp[threadIdx.x] = v;
    __syncthreads();
    for (int off = 1; off < 512; off <<= 1) {
        int t = (threadIdx.x >= off) ? tmp[threadIdx.x - off] : 0;
        __syncthreads();
        tmp[threadIdx.x] += t;
        __syncthreads();
    }
    if (threadIdx.x < nb) bsums[threadIdx.x] = tmp[threadIdx.x] - v;  // exclusive
}

__global__ void k_scan3(int* __restrict__ out, const int* __restrict__ bsums, int n) {
    int gid = blockIdx.x * 256 + threadIdx.x;
    if (gid < n) out[gid] += bsums[blockIdx.x];
    if (gid == 0) out[n] = N_EDGES;
}

__global__ void k_fill(const int* __restrict__ src, const int* __restrict__ dst,
                       const int* __restrict__ offs, int* __restrict__ cursor,
                       int* __restrict__ csr) {
    int e = blockIdx.x * 256 + threadIdx.x;
    if (e < N_EDGES) {
        int d = dst[e];
        int pos = offs[d] + atomicAdd(&cursor[d], 1);
        csr[pos] = src[e];
    }
}

// ---------------- conv layer kernels ----------------

// Y[100000,128] = X[100000,128] @ W[128,128]; 32-row tile/block, 4x4 per thread
__global__ __launch_bounds__(256) void k_gemm(const float* __restrict__ X,
                                              const float* __restrict__ W,
                                              float* __restrict__ Y) {
    __shared__ float Wl[64 * 128];
    __shared__ float Xl[32 * 128];
    int t = threadIdx.x;
    int row0 = blockIdx.x * 32;
    {
        const float4* X4 = (const float4*)(X + (size_t)row0 * D);
        float4* Xl4 = (float4*)Xl;
        for (int i = t; i < 1024; i += 256) Xl4[i] = X4[i];
    }
    int j0 = (t & 31) * 4;
    int r0 = (t >> 5) * 4;
    float acc[4][4] = {};
    for (int kt = 0; kt < 2; ++kt) {
        __syncthreads();
        {
            const float4* W4 = (const float4*)(W + kt * 64 * D);
            float4* Wl4 = (float4*)Wl;
            for (int i = t; i < 2048; i += 256) Wl4[i] = W4[i];
        }
        __syncthreads();
        for (int k = 0; k < 64; ++k) {
            float4 b = *(const float4*)&Wl[k * 128 + j0];
            int kk = kt * 64 + k;
#pragma unroll
            for (int i = 0; i < 4; ++i) {
                float a = Xl[(r0 + i) * 128 + kk];
                acc[i][0] = fmaf(a, b.x, acc[i][0]);
                acc[i][1] = fmaf(a, b.y, acc[i][1]);
                acc[i][2] = fmaf(a, b.z, acc[i][2]);
                acc[i][3] = fmaf(a, b.w, acc[i][3]);
            }
        }
    }
#pragma unroll
    for (int i = 0; i < 4; ++i) {
        float4 v = make_float4(acc[i][0], acc[i][1], acc[i][2], acc[i][3]);
        *(float4*)&Y[(size_t)(row0 + r0 + i) * D + j0] = v;
    }
}

// out[n] = relu(dinv[n]*(sum_e dinv[src]*Y[src] + dinv[n]*Y[n]) + b)
__global__ void k_aggregate(const float* __restrict__ Y, const int* __restrict__ offs,
                            const int* __restrict__ csr, const float* __restrict__ dinv,
                            const float* __restrict__ bias, float* __restrict__ out) {
    int node = blockIdx.x;
    int c = threadIdx.x;  // 128 threads
    int beg = offs[node], end = offs[node + 1];
    float dn = dinv[node];
    float acc = dn * Y[(size_t)node * D + c];  // self loop (x dn at end -> dn^2)
    for (int e = beg; e < end; ++e) {
        int s = csr[e];
        acc = fmaf(dinv[s], Y[(size_t)s * D + c], acc);
    }
    acc = fmaf(acc, dn, bias[c]);
    out[(size_t)node * D + c] = fmaxf(acc, 0.0f);
}

__global__ void k_colstats(const float* __restrict__ x, float* __restrict__ sums,
                           float* __restrict__ sumsq, int n) {
    int c = threadIdx.x & 127;
    int rh = threadIdx.x >> 7;
    float s = 0.f, s2 = 0.f;
    for (int r = blockIdx.x * 2 + rh; r < n; r += gridDim.x * 2) {
        float v = x[(size_t)r * D + c];
        s += v;
        s2 = fmaf(v, v, s2);
    }
    __shared__ float ls[256], ls2[256];
    ls[threadIdx.x] = s;
    ls2[threadIdx.x] = s2;
    __syncthreads();
    if (threadIdx.x < 128) {
        atomicAdd(&sums[c], ls[c] + ls[c + 128]);
        atomicAdd(&sumsq[c], ls2[c] + ls2[c + 128]);
    }
}

__global__ void k_bn_coeffs(const float* __restrict__ sums, const float* __restrict__ sumsq,
                            const float* __restrict__ g, const float* __restrict__ beta,
                            float* __restrict__ a, float* __restrict__ c, int n, int C) {
    int i = threadIdx.x;
    if (i < C) {
        float m = sums[i] / n;
        float v = sumsq[i] / n - m * m;
        float ai = g[i] * rsqrtf(v + EPS);
        a[i] = ai;
        c[i] = beta[i] - m * ai;
    }
}

__global__ void k_bn_apply(float* __restrict__ x, const float* __restrict__ a,
                           const float* __restrict__ c, int n4) {
    int i = blockIdx.x * 256 + threadIdx.x;
    if (i >= n4) return;
    float4 v = ((float4*)x)[i];
    int col = (i << 2) & 127;
    v.x = fmaf(v.x, a[col], c[col]);
    v.y = fmaf(v.y, a[col + 1], c[col + 1]);
    v.z = fmaf(v.z, a[col + 2], c[col + 2]);
    v.w = fmaf(v.w, a[col + 3], c[col + 3]);
    ((float4*)x)[i] = v;
}

// ---------------- pooling + MLP head ----------------

__global__ void k_starts(const int* __restrict__ batch, int* __restrict__ starts) {
    int n = blockIdx.x * 256 + threadIdx.x;
    if (n >= N_NODES) return;
    int b = batch[n];
    int prev = (n == 0) ? -1 : batch[n - 1];
    for (int g = prev + 1; g <= b; ++g) starts[g] = n;
    if (n == N_NODES - 1)
        for (int g = b + 1; g <= N_GRAPHS; ++g) starts[g] = N_NODES;
}

__global__ void k_pool(const float* __restrict__ x, const int* __restrict__ starts,
                       float* __restrict__ pooled) {
    int g = blockIdx.x;
    int c = threadIdx.x;  // 128
    float s = 0.f;
    int e = starts[g + 1];
    for (int n = starts[g]; n < e; ++n) s += x[(size_t)n * D + c];
    pooled[g * D + c] = s;
}

__global__ void k_dense_relu(const float* __restrict__ in, const float* __restrict__ W,
                             const float* __restrict__ b, float* __restrict__ out,
                             int K, int N) {
    int row = blockIdx.x;
    int j = blockIdx.y * 256 + threadIdx.x;
    if (j >= N) return;
    float acc = b[j];
    for (int k = 0; k < K; ++k) acc = fmaf(in[row * K + k], W[k * N + j], acc);
    out[row * N + j] = fmaxf(acc, 0.0f);
}

// single-block BN (stats + normalize) over [rows, C], C<=256
__global__ void k_bn_small(float* __restrict__ x, const float* __restrict__ g,
                           const float* __restrict__ beta, int rows, int C) {
    int c = threadIdx.x;
    if (c >= C) return;
    float s = 0.f, s2 = 0.f;
    for (int r = 0; r < rows; ++r) {
        float v = x[r * C + c];
        s += v;
        s2 = fmaf(v, v, s2);
    }
    float m = s / rows;
    float var = s2 / rows - m * m;
    float a = g[c] * rsqrtf(var + EPS);
    float cc = beta[c] - m * a;
    for (int r = 0; r < rows; ++r) x[r * C + c] = fmaf(x[r * C + c], a, cc);
}

__global__ void k_final(const float* __restrict__ h, const float* __restrict__ Wout,
                        const float* __restrict__ bout, float* __restrict__ out) {
    int g = blockIdx.x * 256 + threadIdx.x;
    if (g >= N_GRAPHS) return;
    float acc = bout[0];
    for (int k = 0; k < DH; ++k) acc = fmaf(h[g * DH + k], Wout[k], acc);
    out[g] = acc;
}

// ---------------- launch ----------------

extern "C" void kernel_launch(void* const* d_in, const int* in_sizes, int n_in,
                              void* d_out, int out_size, void* d_ws, size_t ws_size,
                              hipStream_t stream) {
    const float* x = (const float*)d_in[0];
    const int* ei = (const int*)d_in[1];
    const int* batch = (const int*)d_in[2];
    const float* Wc = (const float*)d_in[3];
    const float* bc = (const float*)d_in[4];
    const float* gc = (const float*)d_in[5];
    const float* bec = (const float*)d_in[6];
    const float* Wh0 = (const float*)d_in[7];
    const float* bh0 = (const float*)d_in[8];
    const float* gh0 = (const float*)d_in[9];
    const float* beh0 = (const float*)d_in[10];
    const float* Wh1 = (const float*)d_in[11];
    const float* bh1 = (const float*)d_in[12];
    const float* gh1 = (const float*)d_in[13];
    const float* beh1 = (const float*)d_in[14];
    const float* Wout = (const float*)d_in[15];
    const float* bout = (const float*)d_in[16];
    float* out = (float*)d_out;

    const int* src = ei;
    const int* dst = ei + N_EDGES;

    char* base = (char*)d_ws;
    size_t woff = 0;
    auto alloc = [&](size_t bytes) -> char* {
        char* p = base + woff;
        woff = (woff + bytes + 255) & ~(size_t)255;
        return p;
    };
    float* bufA = (float*)alloc(sizeof(float) * (size_t)N_NODES * D);
    float* bufY = (float*)alloc(sizeof(float) * (size_t)N_NODES * D);
    float* dinv = (float*)alloc(sizeof(float) * N_NODES);
    int* csr = (int*)alloc(sizeof(int) * N_EDGES);
    int* cnt = (int*)alloc(sizeof(int) * N_NODES);
    int* offs = (int*)alloc(sizeof(int) * (N_NODES + 1));
    int* cursor = (int*)alloc(sizeof(int) * N_NODES);
    int* bsums = (int*)alloc(sizeof(int) * 512);
    float* stats = (float*)alloc(sizeof(float) * 512);  // sums[256] + sumsq[256]
    float* sums = stats;
    float* sumsq = stats + 256;
    float* avec = (float*)alloc(sizeof(float) * 256);
    float* cvec = (float*)alloc(sizeof(float) * 256);
    int* starts = (int*)alloc(sizeof(int) * (N_GRAPHS + 1));
    float* pooled = (float*)alloc(sizeof(float) * N_GRAPHS * D);
    float* h0 = (float*)alloc(sizeof(float) * N_GRAPHS * DH);
    float* h1 = (float*)alloc(sizeof(float) * N_GRAPHS * DH);

    hipMemsetAsync(cnt, 0, sizeof(int) * N_NODES, stream);
    hipMemsetAsync(cursor, 0, sizeof(int) * N_NODES, stream);

    int ebl = (N_EDGES + 255) / 256;
    int nbl = (N_NODES + 255) / 256;
    k_count<<<ebl, 256, 0, stream>>>(dst, cnt);
    k_dinv<<<nbl, 256, 0, stream>>>(cnt, dinv);
    k_scan1<<<nbl, 256, 0, stream>>>(cnt, offs, bsums, N_NODES);
    k_scan2<<<1, 512, 0, stream>>>(bsums, nbl);
    k_scan3<<<nbl, 256, 0, stream>>>(offs, bsums, N_NODES);
    k_fill<<<ebl, 256, 0, stream>>>(src, dst, offs, cursor, csr);

    const float* cur_in = x;
    for (int layer = 0; layer < 3; ++layer) {
        k_gemm<<<N_NODES / 32, 256, 0, stream>>>(cur_in, Wc + layer * D * D, bufY);
        k_aggregate<<<N_NODES, 128, 0, stream>>>(bufY, offs, csr, dinv, bc + layer * D, bufA);
        hipMemsetAsync(stats, 0, sizeof(float) * 512, stream);
        k_colstats<<<512, 256, 0, stream>>>(bufA, sums, sumsq, N_NODES);
        k_bn_coeffs<<<1, 128, 0, stream>>>(sums, sumsq, gc + layer * D, bec + layer * D,
                                           avec, cvec, N_NODES, D);
        k_bn_apply<<<(N_NODES * D / 4 + 255) / 256, 256, 0, stream>>>(bufA, avec, cvec,
                                                                     N_NODES * D / 4);
        cur_in = bufA;
    }

    k_starts<<<nbl, 256, 0, stream>>>(batch, starts);
    k_pool<<<N_GRAPHS, 128, 0, stream>>>(bufA, starts, pooled);
    k_dense_relu<<<dim3(N_GRAPHS, 1), 256, 0, stream>>>(pooled, Wh0, bh0, h0, D, DH);
    k_bn_small<<<1, 256, 0, stream>>>(h0, gh0, beh0, N_GRAPHS, DH);
    k_dense_relu<<<dim3(N_GRAPHS, 1), 256, 0, stream>>>(h0, Wh1, bh1, h1, DH, DH);
    k_bn_small<<<1, 256, 0, stream>>>(h1, gh1, beh1, N_GRAPHS, DH);
    k_final<<<2, 256, 0, stream>>>(h1, Wout, bout, out);
}

// Round 2
// 1210.354 us; speedup vs baseline: 1.4357x; 1.4357x over previous
//
#include <hip/hip_runtime.h>

#define N_NODES 100000
#define N_EDGES 1600000
#define D 128
#define DH 256
#define N_GRAPHS 512
#define EPS 1e-5f

// ---------------- preprocessing ----------------

__global__ void k_count(const int* __restrict__ dst, int* __restrict__ cnt) {
    int e = blockIdx.x * 256 + threadIdx.x;
    if (e < N_EDGES) atomicAdd(&cnt[dst[e]], 1);
}

__global__ void k_dinv(const int* __restrict__ cnt, float* __restrict__ dinv) {
    int i = blockIdx.x * 256 + threadIdx.x;
    if (i < N_NODES) dinv[i] = rsqrtf((float)(cnt[i] + 1));
}

__global__ void k_scan1(const int* __restrict__ in, int* __restrict__ out,
                        int* __restrict__ bsums, int n) {
    __shared__ int tmp[256];
    int gid = blockIdx.x * 256 + threadIdx.x;
    int v = (gid < n) ? in[gid] : 0;
    tmp[threadIdx.x] = v;
    __syncthreads();
    for (int off = 1; off < 256; off <<= 1) {
        int t = (threadIdx.x >= off) ? tmp[threadIdx.x - off] : 0;
        __syncthreads();
        tmp[threadIdx.x] += t;
        __syncthreads();
    }
    if (gid < n) out[gid] = tmp[threadIdx.x] - v;  // exclusive
    if (threadIdx.x == 255) bsums[blockIdx.x] = tmp[255];
}

__global__ void k_scan2(int* __restrict__ bsums, int nb) {
    __shared__ int tmp[512];
    int v = (threadIdx.x < nb) ? bsums[threadIdx.x] : 0;
    tmp[threadIdx.x] = v;
    __syncthreads();
    for (int off = 1; off < 512; off <<= 1) {
        int t = (threadIdx.x >= off) ? tmp[threadIdx.x - off] : 0;
        __syncthreads();
        tmp[threadIdx.x] += t;
        __syncthreads();
    }
    if (threadIdx.x < nb) bsums[threadIdx.x] = tmp[threadIdx.x] - v;  // exclusive
}

__global__ void k_scan3(int* __restrict__ out, const int* __restrict__ bsums, int n) {
    int gid = blockIdx.x * 256 + threadIdx.x;
    if (gid < n) out[gid] += bsums[blockIdx.x];
    if (gid == 0) out[n] = N_EDGES;
}

__global__ void k_fill(const int* __restrict__ src, const int* __restrict__ dst,
                       const int* __restrict__ offs, int* __restrict__ cursor,
                       int* __restrict__ csr) {
    int e = blockIdx.x * 256 + threadIdx.x;
    if (e < N_EDGES) {
        int d = dst[e];
        int pos = offs[d] + atomicAdd(&cursor[d], 1);
        csr[pos] = src[e];
    }
}

// ---------------- conv layer kernels ----------------

// Y[100000,128] = X @ W + r (r: constant row vector from BN fold)
__global__ __launch_bounds__(256) void k_gemm(const float* __restrict__ X,
                                              const float* __restrict__ W,
                                              const float* __restrict__ radd,
                                              float* __restrict__ Y) {
    __shared__ float Wl[64 * 128];
    __shared__ float Xl[32 * 128];
    int t = threadIdx.x;
    int row0 = blockIdx.x * 32;
    {
        const float4* X4 = (const float4*)(X + (size_t)row0 * D);
        float4* Xl4 = (float4*)Xl;
        for (int i = t; i < 1024; i += 256) Xl4[i] = X4[i];
    }
    int j0 = (t & 31) * 4;
    int r0 = (t >> 5) * 4;
    float acc[4][4] = {};
    for (int kt = 0; kt < 2; ++kt) {
        __syncthreads();
        {
            const float4* W4 = (const float4*)(W + kt * 64 * D);
            float4* Wl4 = (float4*)Wl;
            for (int i = t; i < 2048; i += 256) Wl4[i] = W4[i];
        }
        __syncthreads();
        for (int k = 0; k < 64; ++k) {
            float4 b = *(const float4*)&Wl[k * 128 + j0];
            int kk = kt * 64 + k;
#pragma unroll
            for (int i = 0; i < 4; ++i) {
                float a = Xl[(r0 + i) * 128 + kk];
                acc[i][0] = fmaf(a, b.x, acc[i][0]);
                acc[i][1] = fmaf(a, b.y, acc[i][1]);
                acc[i][2] = fmaf(a, b.z, acc[i][2]);
                acc[i][3] = fmaf(a, b.w, acc[i][3]);
            }
        }
    }
    float4 rv = *(const float4*)&radd[j0];
#pragma unroll
    for (int i = 0; i < 4; ++i) {
        float4 v = make_float4(acc[i][0] + rv.x, acc[i][1] + rv.y,
                               acc[i][2] + rv.z, acc[i][3] + rv.w);
        *(float4*)&Y[(size_t)(row0 + r0 + i) * D + j0] = v;
    }
}

// BN fold helpers: Wm[k][j] = a[k]*W[k][j];  r[j] = sum_k c[k]*W[k][j]
__global__ void k_fold_w(const float* __restrict__ a, const float* __restrict__ W,
                         float* __restrict__ Wm) {
    int idx = blockIdx.x * 256 + threadIdx.x;  // 16384
    int k = idx >> 7;
    Wm[idx] = a[k] * W[idx];
}

__global__ void k_fold_r(const float* __restrict__ c, const float* __restrict__ W,
                         float* __restrict__ r) {
    int j = threadIdx.x;  // 128
    float s = 0.f;
    for (int k = 0; k < D; ++k) s = fmaf(c[k], W[k * D + j], s);
    r[j] = s;
}

// out[n] = relu(dn*(sum_e dinv[src]*Y[src] + dn*Y[n]) + b); 8 nodes per block
__global__ __launch_bounds__(256) void k_aggregate(const float4* __restrict__ Y4,
                                                   const int* __restrict__ offs,
                                                   const int* __restrict__ csr,
                                                   const float* __restrict__ dinv,
                                                   const float4* __restrict__ bias4,
                                                   float4* __restrict__ out4) {
    int node = blockIdx.x * 8 + (threadIdx.x >> 5);
    int lane = threadIdx.x & 31;
    int beg = offs[node], end = offs[node + 1];
    float dn = dinv[node];
    float4 y = Y4[(size_t)node * 32 + lane];
    float4 acc = make_float4(dn * y.x, dn * y.y, dn * y.z, dn * y.w);
    for (int e = beg; e < end; ++e) {
        int s = csr[e];
        float ds = dinv[s];
        float4 v = Y4[(size_t)s * 32 + lane];
        acc.x = fmaf(ds, v.x, acc.x);
        acc.y = fmaf(ds, v.y, acc.y);
        acc.z = fmaf(ds, v.z, acc.z);
        acc.w = fmaf(ds, v.w, acc.w);
    }
    float4 b = bias4[lane];
    acc.x = fmaxf(fmaf(acc.x, dn, b.x), 0.f);
    acc.y = fmaxf(fmaf(acc.y, dn, b.y), 0.f);
    acc.z = fmaxf(fmaf(acc.z, dn, b.z), 0.f);
    acc.w = fmaxf(fmaf(acc.w, dn, b.w), 0.f);
    out4[(size_t)node * 32 + lane] = acc;
}

// column sums/sumsq over [n,128], float4, 8 row-groups per block
__global__ void k_colstats(const float4* __restrict__ x4, float* __restrict__ sums,
                           float* __restrict__ sumsq, int n) {
    int lane = threadIdx.x & 31;
    int grp = threadIdx.x >> 5;
    float4 s = make_float4(0, 0, 0, 0), s2 = make_float4(0, 0, 0, 0);
    for (int r = blockIdx.x * 8 + grp; r < n; r += gridDim.x * 8) {
        float4 v = x4[(size_t)r * 32 + lane];
        s.x += v.x; s.y += v.y; s.z += v.z; s.w += v.w;
        s2.x = fmaf(v.x, v.x, s2.x);
        s2.y = fmaf(v.y, v.y, s2.y);
        s2.z = fmaf(v.z, v.z, s2.z);
        s2.w = fmaf(v.w, v.w, s2.w);
    }
    __shared__ float4 ls[256], ls2[256];
    ls[threadIdx.x] = s;
    ls2[threadIdx.x] = s2;
    __syncthreads();
    if (threadIdx.x < 32) {
        float4 a = ls[threadIdx.x], b = ls2[threadIdx.x];
        for (int g = 1; g < 8; ++g) {
            float4 u = ls[g * 32 + threadIdx.x], w = ls2[g * 32 + threadIdx.x];
            a.x += u.x; a.y += u.y; a.z += u.z; a.w += u.w;
            b.x += w.x; b.y += w.y; b.z += w.z; b.w += w.w;
        }
        int c = threadIdx.x * 4;
        atomicAdd(&sums[c], a.x); atomicAdd(&sums[c + 1], a.y);
        atomicAdd(&sums[c + 2], a.z); atomicAdd(&sums[c + 3], a.w);
        atomicAdd(&sumsq[c], b.x); atomicAdd(&sumsq[c + 1], b.y);
        atomicAdd(&sumsq[c + 2], b.z); atomicAdd(&sumsq[c + 3], b.w);
    }
}

__global__ void k_bn_coeffs(const float* __restrict__ sums, const float* __restrict__ sumsq,
                            const float* __restrict__ g, const float* __restrict__ beta,
                            float* __restrict__ a, float* __restrict__ c, int n, int C) {
    int i = threadIdx.x;
    if (i < C) {
        float m = sums[i] / n;
        float v = sumsq[i] / n - m * m;
        float ai = g[i] * rsqrtf(v + EPS);
        a[i] = ai;
        c[i] = beta[i] - m * ai;
    }
}

// ---------------- pooling + MLP head ----------------

__global__ void k_starts(const int* __restrict__ batch, int* __restrict__ starts) {
    int n = blockIdx.x * 256 + threadIdx.x;
    if (n >= N_NODES) return;
    int b = batch[n];
    int prev = (n == 0) ? -1 : batch[n - 1];
    for (int g = prev + 1; g <= b; ++g) starts[g] = n;
    if (n == N_NODES - 1)
        for (int g = b + 1; g <= N_GRAPHS; ++g) starts[g] = N_NODES;
}

// pooled = a * sum(x) + cnt*c  (layer-3 BN folded in); 8 graphs per block
__global__ void k_pool(const float4* __restrict__ x4, const int* __restrict__ starts,
                       const float4* __restrict__ a4, const float4* __restrict__ c4,
                       float4* __restrict__ pooled4) {
    int g = blockIdx.x * 8 + (threadIdx.x >> 5);
    int lane = threadIdx.x & 31;
    int beg = starts[g], end = starts[g + 1];
    float4 s = make_float4(0, 0, 0, 0);
    for (int n = beg; n < end; ++n) {
        float4 v = x4[(size_t)n * 32 + lane];
        s.x += v.x; s.y += v.y; s.z += v.z; s.w += v.w;
    }
    float cnt = (float)(end - beg);
    float4 a = a4[lane], c = c4[lane];
    pooled4[g * 32 + lane] = make_float4(fmaf(a.x, s.x, cnt * c.x),
                                         fmaf(a.y, s.y, cnt * c.y),
                                         fmaf(a.z, s.z, cnt * c.z),
                                         fmaf(a.w, s.w, cnt * c.w));
}

__global__ void k_dense_relu(const float* __restrict__ in, const float* __restrict__ W,
                             const float* __restrict__ b, float* __restrict__ out,
                             int K, int N) {
    int row = blockIdx.x;
    int j = threadIdx.x;
    if (j >= N) return;
    float acc = b[j];
    for (int k = 0; k < K; ++k) acc = fmaf(in[row * K + k], W[k * N + j], acc);
    out[row * N + j] = fmaxf(acc, 0.0f);
}

// head BN stats: [rows,256]; 8 rows per block, atomics into sums/sumsq
__global__ void k_head_stats(const float* __restrict__ x, float* __restrict__ sums,
                             float* __restrict__ sumsq, int rows) {
    int c = threadIdx.x;  // 256
    float s = 0.f, s2 = 0.f;
    int r0 = blockIdx.x * 8;
    int r1 = min(r0 + 8, rows);
    for (int r = r0; r < r1; ++r) {
        float v = x[r * DH + c];
        s += v;
        s2 = fmaf(v, v, s2);
    }
    atomicAdd(&sums[c], s);
    atomicAdd(&sumsq[c], s2);
}

__global__ void k_head_apply(float* __restrict__ x, const float* __restrict__ a,
                             const float* __restrict__ c) {
    int i = blockIdx.x * 256 + threadIdx.x;  // over 512*256/4
    float4 v = ((float4*)x)[i];
    int col = (i << 2) & 255;
    v.x = fmaf(v.x, a[col], c[col]);
    v.y = fmaf(v.y, a[col + 1], c[col + 1]);
    v.z = fmaf(v.z, a[col + 2], c[col + 2]);
    v.w = fmaf(v.w, a[col + 3], c[col + 3]);
    ((float4*)x)[i] = v;
}

__global__ void k_final(const float* __restrict__ h, const float* __restrict__ Wout,
                        const float* __restrict__ bout, float* __restrict__ out) {
    int g = blockIdx.x * 256 + threadIdx.x;
    if (g >= N_GRAPHS) return;
    float acc = bout[0];
    for (int k = 0; k < DH; ++k) acc = fmaf(h[g * DH + k], Wout[k], acc);
    out[g] = acc;
}

// ---------------- launch ----------------

extern "C" void kernel_launch(void* const* d_in, const int* in_sizes, int n_in,
                              void* d_out, int out_size, void* d_ws, size_t ws_size,
                              hipStream_t stream) {
    const float* x = (const float*)d_in[0];
    const int* ei = (const int*)d_in[1];
    const int* batch = (const int*)d_in[2];
    const float* Wc = (const float*)d_in[3];
    const float* bc = (const float*)d_in[4];
    const float* gc = (const float*)d_in[5];
    const float* bec = (const float*)d_in[6];
    const float* Wh0 = (const float*)d_in[7];
    const float* bh0 = (const float*)d_in[8];
    const float* gh0 = (const float*)d_in[9];
    const float* beh0 = (const float*)d_in[10];
    const float* Wh1 = (const float*)d_in[11];
    const float* bh1 = (const float*)d_in[12];
    const float* gh1 = (const float*)d_in[13];
    const float* beh1 = (const float*)d_in[14];
    const float* Wout = (const float*)d_in[15];
    const float* bout = (const float*)d_in[16];
    float* out = (float*)d_out;

    const int* src = ei;
    const int* dst = ei + N_EDGES;

    char* base = (char*)d_ws;
    size_t woff = 0;
    auto alloc = [&](size_t bytes) -> char* {
        char* p = base + woff;
        woff = (woff + bytes + 255) & ~(size_t)255;
        return p;
    };
    float* bufA = (float*)alloc(sizeof(float) * (size_t)N_NODES * D);
    float* bufY = (float*)alloc(sizeof(float) * (size_t)N_NODES * D);
    float* dinv = (float*)alloc(sizeof(float) * N_NODES);
    int* csr = (int*)alloc(sizeof(int) * N_EDGES);
    int* cnt = (int*)alloc(sizeof(int) * N_NODES);
    int* offs = (int*)alloc(sizeof(int) * (N_NODES + 1));
    int* cursor = (int*)alloc(sizeof(int) * N_NODES);
    int* bsums = (int*)alloc(sizeof(int) * 512);
    float* stats = (float*)alloc(sizeof(float) * 512);
    float* sums = stats;
    float* sumsq = stats + 256;
    float* avec = (float*)alloc(sizeof(float) * 256);
    float* cvec = (float*)alloc(sizeof(float) * 256);
    float* zeros_r = (float*)alloc(sizeof(float) * 128);
    float* Wm = (float*)alloc(sizeof(float) * D * D);
    float* rvec = (float*)alloc(sizeof(float) * 128);
    int* starts = (int*)alloc(sizeof(int) * (N_GRAPHS + 1));
    float* pooled = (float*)alloc(sizeof(float) * N_GRAPHS * D);
    float* h0 = (float*)alloc(sizeof(float) * N_GRAPHS * DH);
    float* h1 = (float*)alloc(sizeof(float) * N_GRAPHS * DH);

    hipMemsetAsync(cnt, 0, sizeof(int) * N_NODES, stream);
    hipMemsetAsync(cursor, 0, sizeof(int) * N_NODES, stream);
    hipMemsetAsync(zeros_r, 0, sizeof(float) * 128, stream);

    int ebl = (N_EDGES + 255) / 256;
    int nbl = (N_NODES + 255) / 256;
    k_count<<<ebl, 256, 0, stream>>>(dst, cnt);
    k_dinv<<<nbl, 256, 0, stream>>>(cnt, dinv);
    k_scan1<<<nbl, 256, 0, stream>>>(cnt, offs, bsums, N_NODES);
    k_scan2<<<1, 512, 0, stream>>>(bsums, nbl);
    k_scan3<<<nbl, 256, 0, stream>>>(offs, bsums, N_NODES);
    k_fill<<<ebl, 256, 0, stream>>>(src, dst, offs, cursor, csr);

    const float* cur_in = x;
    for (int layer = 0; layer < 3; ++layer) {
        const float* Wuse;
        const float* ruse;
        if (layer == 0) {
            Wuse = Wc;
            ruse = zeros_r;
        } else {
            k_fold_w<<<64, 256, 0, stream>>>(avec, Wc + layer * D * D, Wm);
            k_fold_r<<<1, 128, 0, stream>>>(cvec, Wc + layer * D * D, rvec);
            Wuse = Wm;
            ruse = rvec;
        }
        k_gemm<<<N_NODES / 32, 256, 0, stream>>>(cur_in, Wuse, ruse, bufY);
        k_aggregate<<<N_NODES / 8, 256, 0, stream>>>(
            (const float4*)bufY, offs, csr, dinv, (const float4*)(bc + layer * D),
            (float4*)bufA);
        hipMemsetAsync(stats, 0, sizeof(float) * 512, stream);
        k_colstats<<<256, 256, 0, stream>>>((const float4*)bufA, sums, sumsq, N_NODES);
        k_bn_coeffs<<<1, 128, 0, stream>>>(sums, sumsq, gc + layer * D, bec + layer * D,
                                           avec, cvec, N_NODES, D);
        cur_in = bufA;
    }

    k_starts<<<nbl, 256, 0, stream>>>(batch, starts);
    k_pool<<<N_GRAPHS / 8, 256, 0, stream>>>((const float4*)bufA, starts,
                                             (const float4*)avec, (const float4*)cvec,
                                             (float4*)pooled);

    k_dense_relu<<<N_GRAPHS, 256, 0, stream>>>(pooled, Wh0, bh0, h0, D, DH);
    hipMemsetAsync(stats, 0, sizeof(float) * 512, stream);
    k_head_stats<<<64, 256, 0, stream>>>(h0, sums, sumsq, N_GRAPHS);
    k_bn_coeffs<<<1, 256, 0, stream>>>(sums, sumsq, gh0, beh0, avec, cvec, N_GRAPHS, DH);
    k_head_apply<<<N_GRAPHS * DH / 4 / 256, 256, 0, stream>>>(h0, avec, cvec);

    k_dense_relu<<<N_GRAPHS, 256, 0, stream>>>(h0, Wh1, bh1, h1, DH, DH);
    hipMemsetAsync(stats, 0, sizeof(float) * 512, stream);
    k_head_stats<<<64, 256, 0, stream>>>(h1, sums, sumsq, N_GRAPHS);
    k_bn_coeffs<<<1, 256, 0, stream>>>(sums, sumsq, gh1, beh1, avec, cvec, N_GRAPHS, DH);
    k_head_apply<<<N_GRAPHS * DH / 4 / 256, 256, 0, stream>>>(h1, avec, cvec);

    k_final<<<2, 256, 0, stream>>>(h1, Wout, bout, out);
}

// Round 3
// 862.156 us; speedup vs baseline: 2.0155x; 1.4039x over previous
//
#include <hip/hip_runtime.h>

#define N_NODES 100000
#define N_EDGES 1600000
#define D 128
#define DH 256
#define N_GRAPHS 512
#define EPS 1e-5f

typedef _Float16 h8 __attribute__((ext_vector_type(8)));
typedef float f4 __attribute__((ext_vector_type(4)));

// ---------------- preprocessing ----------------

__global__ void k_count(const int* __restrict__ dst, int* __restrict__ cnt) {
    int e = blockIdx.x * 256 + threadIdx.x;
    if (e < N_EDGES) atomicAdd(&cnt[dst[e]], 1);
}

__global__ void k_dinv(const int* __restrict__ cnt, float* __restrict__ dinv) {
    int i = blockIdx.x * 256 + threadIdx.x;
    if (i < N_NODES) dinv[i] = rsqrtf((float)(cnt[i] + 1));
}

__global__ void k_scan1(const int* __restrict__ in, int* __restrict__ out,
                        int* __restrict__ bsums, int n) {
    __shared__ int tmp[256];
    int gid = blockIdx.x * 256 + threadIdx.x;
    int v = (gid < n) ? in[gid] : 0;
    tmp[threadIdx.x] = v;
    __syncthreads();
    for (int off = 1; off < 256; off <<= 1) {
        int t = (threadIdx.x >= off) ? tmp[threadIdx.x - off] : 0;
        __syncthreads();
        tmp[threadIdx.x] += t;
        __syncthreads();
    }
    if (gid < n) out[gid] = tmp[threadIdx.x] - v;
    if (threadIdx.x == 255) bsums[blockIdx.x] = tmp[255];
}

__global__ void k_scan2(int* __restrict__ bsums, int nb) {
    __shared__ int tmp[512];
    int v = (threadIdx.x < nb) ? bsums[threadIdx.x] : 0;
    tmp[threadIdx.x] = v;
    __syncthreads();
    for (int off = 1; off < 512; off <<= 1) {
        int t = (threadIdx.x >= off) ? tmp[threadIdx.x - off] : 0;
        __syncthreads();
        tmp[threadIdx.x] += t;
        __syncthreads();
    }
    if (threadIdx.x < nb) bsums[threadIdx.x] = tmp[threadIdx.x] - v;
}

__global__ void k_scan3(int* __restrict__ out, const int* __restrict__ bsums, int n) {
    int gid = blockIdx.x * 256 + threadIdx.x;
    if (gid < n) out[gid] += bsums[blockIdx.x];
    if (gid == 0) out[n] = N_EDGES;
}

__global__ void k_fill(const int* __restrict__ src, const int* __restrict__ dst,
                       const int* __restrict__ offs, int* __restrict__ cursor,
                       int* __restrict__ csr) {
    int e = blockIdx.x * 256 + threadIdx.x;
    if (e < N_EDGES) {
        int d = dst[e];
        int pos = offs[d] + atomicAdd(&cursor[d], 1);
        csr[pos] = src[e];
    }
}

// cast fp32 x -> fp16 (half8 per thread)
__global__ void k_cast(const float4* __restrict__ x4, h8* __restrict__ xh, int n8) {
    int i = blockIdx.x * 256 + threadIdx.x;
    if (i >= n8) return;
    float4 a = x4[2 * i], b = x4[2 * i + 1];
    h8 o;
    o[0] = (_Float16)a.x; o[1] = (_Float16)a.y; o[2] = (_Float16)a.z; o[3] = (_Float16)a.w;
    o[4] = (_Float16)b.x; o[5] = (_Float16)b.y; o[6] = (_Float16)b.z; o[7] = (_Float16)b.w;
    xh[i] = o;
}

// ---------------- BN fold: WT[n][k] = a[k]*W[k][n] (fp16); r[j]=sum_k c[k]W[k][j]
__global__ void k_fold_wt(const float* __restrict__ W, const float* __restrict__ a,
                          int use_bn, _Float16* __restrict__ WT) {
    int idx = blockIdx.x * 256 + threadIdx.x;  // 16384
    int n = idx >> 7, k = idx & 127;
    float s = use_bn ? a[k] : 1.0f;
    WT[idx] = (_Float16)(s * W[k * D + n]);
}

__global__ void k_fold_r(const float* __restrict__ W, const float* __restrict__ c,
                         int use_bn, float* __restrict__ r) {
    int j = threadIdx.x;  // 128
    float s = 0.f;
    if (use_bn)
        for (int k = 0; k < D; ++k) s = fmaf(c[k], W[k * D + j], s);
    r[j] = s;
}

// ---------------- MFMA GEMM: Y[nrows,128] = X @ W + r, fp16 in/out ----------
__global__ __launch_bounds__(256) void k_gemm(const _Float16* __restrict__ X,
                                              const _Float16* __restrict__ WT,
                                              const float* __restrict__ radd,
                                              _Float16* __restrict__ Y, int nrows) {
    __shared__ _Float16 Wl[128][136];
    __shared__ _Float16 Yl[64][136];
    int t = threadIdx.x;
    // stage WT (row-major [n][k], 128x128) into padded LDS
    {
        const h8* src = (const h8*)WT;
        for (int i = t; i < 128 * 16; i += 256) {
            int r = i >> 4, c = i & 15;
            *(h8*)&Wl[r][c * 8] = src[i];
        }
    }
    int wave = t >> 6;
    int lane = t & 63;
    int l15 = lane & 15;
    int quad = lane >> 4;
    int rowblk = blockIdx.x * 64;
    int row0 = rowblk + wave * 16;

    h8 zero8;
#pragma unroll
    for (int j = 0; j < 8; ++j) zero8[j] = (_Float16)0;

    h8 a[4];
    bool inb = (row0 + l15) < nrows;
    const _Float16* xrow = X + (size_t)(row0 + l15) * D + quad * 8;
#pragma unroll
    for (int kt = 0; kt < 4; ++kt) a[kt] = inb ? *(const h8*)(xrow + kt * 32) : zero8;

    __syncthreads();

    f4 acc[8];
#pragma unroll
    for (int n = 0; n < 8; ++n) {
        acc[n][0] = 0.f; acc[n][1] = 0.f; acc[n][2] = 0.f; acc[n][3] = 0.f;
#pragma unroll
        for (int kt = 0; kt < 4; ++kt) {
            h8 b = *(const h8*)&Wl[n * 16 + l15][kt * 32 + quad * 8];
            acc[n] = __builtin_amdgcn_mfma_f32_16x16x32_f16(a[kt], b, acc[n], 0, 0, 0);
        }
    }
    // epilogue: + radd, to LDS tile (C/D: col=lane&15, row=quad*4+reg)
#pragma unroll
    for (int n = 0; n < 8; ++n) {
        float r = radd[n * 16 + l15];
#pragma unroll
        for (int i = 0; i < 4; ++i)
            Yl[wave * 16 + quad * 4 + i][n * 16 + l15] = (_Float16)(acc[n][i] + r);
    }
    __syncthreads();
    for (int i = t; i < 64 * 16; i += 256) {
        int r = i >> 4, c = i & 15;
        if (rowblk + r < nrows)
            *(h8*)&Y[(size_t)(rowblk + r) * D + c * 8] = *(h8*)&Yl[r][c * 8];
    }
}

// ---------------- aggregate + relu + fused BN partial stats ----------------
// 16 lanes/node, 16 nodes/block
__global__ __launch_bounds__(256) void k_aggregate(const h8* __restrict__ Y8,
                                                   const int* __restrict__ offs,
                                                   const int* __restrict__ csr,
                                                   const float* __restrict__ dinv,
                                                   const float* __restrict__ bias,
                                                   h8* __restrict__ A8,
                                                   float* __restrict__ part) {
    int grp = threadIdx.x >> 4;
    int lane = threadIdx.x & 15;
    int node = blockIdx.x * 16 + grp;
    int beg = offs[node], end = offs[node + 1];
    float dn = dinv[node];
    float acc[8];
    h8 y = Y8[(size_t)node * 16 + lane];
#pragma unroll
    for (int i = 0; i < 8; ++i) acc[i] = dn * (float)y[i];
    for (int e = beg; e < end; ++e) {
        int s = csr[e];
        float ds = dinv[s];
        h8 v = Y8[(size_t)s * 16 + lane];
#pragma unroll
        for (int i = 0; i < 8; ++i) acc[i] = fmaf(ds, (float)v[i], acc[i]);
    }
    __shared__ float red[16][128];
    h8 o;
#pragma unroll
    for (int i = 0; i < 8; ++i) {
        float v = fmaxf(fmaf(acc[i], dn, bias[lane * 8 + i]), 0.f);
        o[i] = (_Float16)v;
        red[grp][lane * 8 + i] = v;
    }
    A8[(size_t)node * 16 + lane] = o;
    __syncthreads();
    if (threadIdx.x < 128) {
        int c = threadIdx.x;
        float s = 0.f, s2 = 0.f;
#pragma unroll
        for (int g = 0; g < 16; ++g) {
            float v = red[g][c];
            s += v;
            s2 = fmaf(v, v, s2);
        }
        float* p = part + (size_t)(blockIdx.x & 31) * 256;
        atomicAdd(&p[c], s);
        atomicAdd(&p[128 + c], s2);
    }
}

// generic BN coeff: sums over stripes; part[st*stride + i] / part[st*stride+coff+i]
__global__ void k_bn_coeffs(const float* __restrict__ part, int stripes, int stride,
                            int coff, const float* __restrict__ g,
                            const float* __restrict__ beta, float* __restrict__ a,
                            float* __restrict__ c, float inv_n) {
    int i = threadIdx.x;
    float s = 0.f, s2 = 0.f;
    for (int st = 0; st < stripes; ++st) {
        s += part[st * stride + i];
        s2 += part[st * stride + coff + i];
    }
    float m = s * inv_n;
    float v = s2 * inv_n - m * m;
    float ai = g[i] * rsqrtf(v + EPS);
    a[i] = ai;
    c[i] = beta[i] - m * ai;
}

// ---------------- pooling + MLP head ----------------

__global__ void k_starts(const int* __restrict__ batch, int* __restrict__ starts) {
    int n = blockIdx.x * 256 + threadIdx.x;
    if (n >= N_NODES) return;
    int b = batch[n];
    int prev = (n == 0) ? -1 : batch[n - 1];
    for (int g = prev + 1; g <= b; ++g) starts[g] = n;
    if (n == N_NODES - 1)
        for (int g = b + 1; g <= N_GRAPHS; ++g) starts[g] = N_NODES;
}

// pooled[g] = a * sum(x_fp16) + cnt*c ; 8 graphs/block, 16 lanes/graph (128 thr)
__global__ void k_pool(const h8* __restrict__ x8, const int* __restrict__ starts,
                       const float* __restrict__ a, const float* __restrict__ c,
                       float* __restrict__ pooled) {
    int grp = threadIdx.x >> 4;
    int lane = threadIdx.x & 15;
    int g = blockIdx.x * 8 + grp;
    int beg = starts[g], end = starts[g + 1];
    float s[8] = {};
    for (int n = beg; n < end; ++n) {
        h8 v = x8[(size_t)n * 16 + lane];
#pragma unroll
        for (int i = 0; i < 8; ++i) s[i] += (float)v[i];
    }
    float cnt = (float)(end - beg);
#pragma unroll
    for (int i = 0; i < 8; ++i) {
        int ch = lane * 8 + i;
        pooled[g * D + ch] = fmaf(a[ch], s[i], cnt * c[ch]);
    }
}

__global__ void k_dense_relu(const float* __restrict__ in, const float* __restrict__ W,
                             const float* __restrict__ b, float* __restrict__ out,
                             int K, int N) {
    int row = blockIdx.x;
    int j = threadIdx.x;
    if (j >= N) return;
    float acc = b[j];
    for (int k = 0; k < K; ++k) acc = fmaf(in[row * K + k], W[k * N + j], acc);
    out[row * N + j] = fmaxf(acc, 0.0f);
}

__global__ void k_head_stats(const float* __restrict__ x, float* __restrict__ sums,
                             float* __restrict__ sumsq, int rows) {
    int c = threadIdx.x;  // 256
    float s = 0.f, s2 = 0.f;
    int r0 = blockIdx.x * 8;
    int r1 = min(r0 + 8, rows);
    for (int r = r0; r < r1; ++r) {
        float v = x[r * DH + c];
        s += v;
        s2 = fmaf(v, v, s2);
    }
    atomicAdd(&sums[c], s);
    atomicAdd(&sumsq[c], s2);
}

__global__ void k_head_apply(float* __restrict__ x, const float* __restrict__ a,
                             const float* __restrict__ c) {
    int i = blockIdx.x * 256 + threadIdx.x;
    float4 v = ((float4*)x)[i];
    int col = (i << 2) & 255;
    v.x = fmaf(v.x, a[col], c[col]);
    v.y = fmaf(v.y, a[col + 1], c[col + 1]);
    v.z = fmaf(v.z, a[col + 2], c[col + 2]);
    v.w = fmaf(v.w, a[col + 3], c[col + 3]);
    ((float4*)x)[i] = v;
}

__global__ void k_final(const float* __restrict__ h, const float* __restrict__ Wout,
                        const float* __restrict__ bout, float* __restrict__ out) {
    int g = blockIdx.x * 256 + threadIdx.x;
    if (g >= N_GRAPHS) return;
    float acc = bout[0];
    for (int k = 0; k < DH; ++k) acc = fmaf(h[g * DH + k], Wout[k], acc);
    out[g] = acc;
}

// ---------------- launch ----------------

extern "C" void kernel_launch(void* const* d_in, const int* in_sizes, int n_in,
                              void* d_out, int out_size, void* d_ws, size_t ws_size,
                              hipStream_t stream) {
    const float* x = (const float*)d_in[0];
    const int* ei = (const int*)d_in[1];
    const int* batch = (const int*)d_in[2];
    const float* Wc = (const float*)d_in[3];
    const float* bc = (const float*)d_in[4];
    const float* gc = (const float*)d_in[5];
    const float* bec = (const float*)d_in[6];
    const float* Wh0 = (const float*)d_in[7];
    const float* bh0 = (const float*)d_in[8];
    const float* gh0 = (const float*)d_in[9];
    const float* beh0 = (const float*)d_in[10];
    const float* Wh1 = (const float*)d_in[11];
    const float* bh1 = (const float*)d_in[12];
    const float* gh1 = (const float*)d_in[13];
    const float* beh1 = (const float*)d_in[14];
    const float* Wout = (const float*)d_in[15];
    const float* bout = (const float*)d_in[16];
    float* out = (float*)d_out;

    const int* src = ei;
    const int* dst = ei + N_EDGES;

    char* base = (char*)d_ws;
    size_t woff = 0;
    auto alloc = [&](size_t bytes) -> char* {
        char* p = base + woff;
        woff = (woff + bytes + 255) & ~(size_t)255;
        return p;
    };
    _Float16* xh = (_Float16*)alloc(sizeof(_Float16) * (size_t)N_NODES * D);
    _Float16* bufY = (_Float16*)alloc(sizeof(_Float16) * (size_t)N_NODES * D);
    _Float16* bufA = (_Float16*)alloc(sizeof(_Float16) * (size_t)N_NODES * D);
    float* dinv = (float*)alloc(sizeof(float) * N_NODES);
    int* csr = (int*)alloc(sizeof(int) * N_EDGES);
    int* cnt = (int*)alloc(sizeof(int) * N_NODES);
    int* offs = (int*)alloc(sizeof(int) * (N_NODES + 1));
    int* cursor = (int*)alloc(sizeof(int) * N_NODES);
    int* bsums = (int*)alloc(sizeof(int) * 512);
    float* part = (float*)alloc(sizeof(float) * 32 * 256);  // striped conv BN partials
    float* stats = (float*)alloc(sizeof(float) * 512);      // head BN sums/sumsq
    float* sums = stats;
    float* sumsq = stats + 256;
    float* avec = (float*)alloc(sizeof(float) * 256);
    float* cvec = (float*)alloc(sizeof(float) * 256);
    _Float16* WT = (_Float16*)alloc(sizeof(_Float16) * D * D);
    float* rvec = (float*)alloc(sizeof(float) * 128);
    int* starts = (int*)alloc(sizeof(int) * (N_GRAPHS + 1));
    float* pooled = (float*)alloc(sizeof(float) * N_GRAPHS * D);
    float* h0 = (float*)alloc(sizeof(float) * N_GRAPHS * DH);
    float* h1 = (float*)alloc(sizeof(float) * N_GRAPHS * DH);

    hipMemsetAsync(cnt, 0, sizeof(int) * N_NODES, stream);
    hipMemsetAsync(cursor, 0, sizeof(int) * N_NODES, stream);

    int ebl = (N_EDGES + 255) / 256;
    int nbl = (N_NODES + 255) / 256;
    k_count<<<ebl, 256, 0, stream>>>(dst, cnt);
    k_dinv<<<nbl, 256, 0, stream>>>(cnt, dinv);
    k_scan1<<<nbl, 256, 0, stream>>>(cnt, offs, bsums, N_NODES);
    k_scan2<<<1, 512, 0, stream>>>(bsums, nbl);
    k_scan3<<<nbl, 256, 0, stream>>>(offs, bsums, N_NODES);
    k_fill<<<ebl, 256, 0, stream>>>(src, dst, offs, cursor, csr);
    k_cast<<<(N_NODES * D / 8 + 255) / 256, 256, 0, stream>>>((const float4*)x,
                                                              (h8*)xh, N_NODES * D / 8);

    const _Float16* cur_in = xh;
    int gemm_grid = (N_NODES + 63) / 64;
    for (int layer = 0; layer < 3; ++layer) {
        k_fold_wt<<<64, 256, 0, stream>>>(Wc + layer * D * D, avec, layer > 0, WT);
        k_fold_r<<<1, 128, 0, stream>>>(Wc + layer * D * D, cvec, layer > 0, rvec);
        k_gemm<<<gemm_grid, 256, 0, stream>>>(cur_in, WT, rvec, bufY, N_NODES);
        hipMemsetAsync(part, 0, sizeof(float) * 32 * 256, stream);
        k_aggregate<<<N_NODES / 16, 256, 0, stream>>>(
            (const h8*)bufY, offs, csr, dinv, bc + layer * D, (h8*)bufA, part);
        k_bn_coeffs<<<1, 128, 0, stream>>>(part, 32, 256, 128, gc + layer * D,
                                           bec + layer * D, avec, cvec, 1.0f / N_NODES);
        cur_in = bufA;
    }

    k_starts<<<nbl, 256, 0, stream>>>(batch, starts);
    k_pool<<<N_GRAPHS / 8, 128, 0, stream>>>((const h8*)bufA, starts, avec, cvec, pooled);

    k_dense_relu<<<N_GRAPHS, 256, 0, stream>>>(pooled, Wh0, bh0, h0, D, DH);
    hipMemsetAsync(stats, 0, sizeof(float) * 512, stream);
    k_head_stats<<<64, 256, 0, stream>>>(h0, sums, sumsq, N_GRAPHS);
    k_bn_coeffs<<<1, 256, 0, stream>>>(stats, 1, 512, 256, gh0, beh0, avec, cvec,
                                       1.0f / N_GRAPHS);
    k_head_apply<<<N_GRAPHS * DH / 4 / 256, 256, 0, stream>>>(h0, avec, cvec);

    k_dense_relu<<<N_GRAPHS, 256, 0, stream>>>(h0, Wh1, bh1, h1, DH, DH);
    hipMemsetAsync(stats, 0, sizeof(float) * 512, stream);
    k_head_stats<<<64, 256, 0, stream>>>(h1, sums, sumsq, N_GRAPHS);
    k_bn_coeffs<<<1, 256, 0, stream>>>(stats, 1, 512, 256, gh1, beh1, avec, cvec,
                                       1.0f / N_GRAPHS);
    k_head_apply<<<N_GRAPHS * DH / 4 / 256, 256, 0, stream>>>(h1, avec, cvec);

    k_final<<<2, 256, 0, stream>>>(h1, Wout, bout, out);
}